// Round 1
// baseline (153.337 us; speedup 1.0000x reference)
//
#include <hip/hip_runtime.h>

// MTCNN proposal: score threshold + greedy NMS + bbox regression on a 96x96 grid.
//
// Key structural facts (exact, from the reference's arithmetic):
//  - x1 = rint(2c/0.6), x2 = rint((2c+12)/0.6): every box is exactly 21x21,
//    grid pitch alternates 3/4 px, any 3 consecutive cells span exactly 10 px.
//  - IoU>0.5 for two 441-area boxes <=> inter > 294; at >=3-cell distance
//    inter <= 11*21 = 231 < 294. So NMS interactions are confined to a
//    5x5 (±2 cell) window -> degree-<=24 local graph.
//  - Greedy NMS (only KEPT boxes suppress) == unique fixpoint of:
//      kept[i] = valid[i] && all higher-priority overlapping neighbors not kept
//    with priority = (score desc, flat index asc)  [argsort is stable].
//    Solved by monotone 3-state relaxation (UNDEC/KEPT/SUPP) to fixpoint —
//    no sort, no 9216^2 IoU matrix, no serial scan.
//
// All box coords/areas/intersections are small integer-valued f32 => exact,
// so every IoU comparison matches the reference bit-for-bit.

namespace {

constexpr int Hh = 96, Ww = 96, Nn = Hh * Ww;
constexpr float THR_SCORE = 0.6f;
constexpr float THR_NMS = 0.5f;
constexpr int NTHREADS = 1024;

__global__ __launch_bounds__(NTHREADS) void mtcnn_nms_kernel(
    const float* __restrict__ cls_prob,
    const float* __restrict__ bbox_pred,
    float* __restrict__ out)
{
  __shared__ float s_lo[Ww];              // x1 (== y1 by row) table
  __shared__ float s_hi[Ww];              // x2 (== y2 by row) table
  __shared__ unsigned int s_mask[Nn];     // 25-bit dominating-overlap mask
  __shared__ unsigned char s_status[Nn];  // 0=UNDEC, 1=KEPT, 2=SUPP
  __shared__ int s_changed;

  const int tid = threadIdx.x;

  // Coordinate tables (same formula for rows and cols).
  if (tid < Ww) {
    float c = (float)tid;
    s_lo[tid] = rintf((2.0f * c) / 0.6f);
    s_hi[tid] = rintf((2.0f * c + 12.0f) / 0.6f);
  }
  // Status init: invalid boxes are final SUPP.
  for (int n = tid; n < Nn; n += NTHREADS) {
    s_status[n] = (cls_prob[n] > THR_SCORE) ? (unsigned char)0 : (unsigned char)2;
  }
  __syncthreads();

  // Per-cell suppressor mask: bit b (5x5 window, row-major, center=12) set iff
  // neighbor is valid, has higher priority, and IoU > 0.5 (exact f32 math).
  for (int n = tid; n < Nn; n += NTHREADS) {
    unsigned int m = 0;
    float si = cls_prob[n];
    if (si > THR_SCORE) {
      int r = n / Ww, c = n - r * Ww;
      float x1 = s_lo[c], x2 = s_hi[c], y1 = s_lo[r], y2 = s_hi[r];
      float area_i = (x2 - x1 + 1.0f) * (y2 - y1 + 1.0f);
      int bit = 0;
      for (int dr = -2; dr <= 2; ++dr) {
        for (int dc = -2; dc <= 2; ++dc, ++bit) {
          if (dr == 0 && dc == 0) continue;
          int rr = r + dr, cc = c + dc;
          if (rr < 0 || rr >= Hh || cc < 0 || cc >= Ww) continue;
          int j = rr * Ww + cc;
          float sj = cls_prob[j];
          if (!(sj > THR_SCORE)) continue;               // only valid boxes suppress
          bool dom = (sj > si) || (sj == si && j < n);   // stable-sort priority
          if (!dom) continue;
          float xj1 = s_lo[cc], xj2 = s_hi[cc], yj1 = s_lo[rr], yj2 = s_hi[rr];
          float xx1 = fmaxf(x1, xj1), yy1 = fmaxf(y1, yj1);
          float xx2 = fminf(x2, xj2), yy2 = fminf(y2, yj2);
          float iw = fmaxf(xx2 - xx1 + 1.0f, 0.0f);
          float ih = fmaxf(yy2 - yy1 + 1.0f, 0.0f);
          float inter = iw * ih;
          float area_j = (xj2 - xj1 + 1.0f) * (yj2 - yj1 + 1.0f);
          float iou = inter / (area_i + area_j - inter);
          if (iou > THR_NMS) m |= (1u << bit);
        }
      }
    }
    s_mask[n] = m;
  }
  __syncthreads();

  // Monotone relaxation to fixpoint. Decisions are final => in-place updates
  // (benign races: a stale UNDEC read only delays convergence, never corrupts).
  // Progress guarantee: the highest-priority UNDEC cell always resolves each
  // round, so <= Nn rounds; cap is far beyond that. Break is block-uniform.
  for (int round = 0; round < 10000; ++round) {
    if (tid == 0) s_changed = 0;
    __syncthreads();
    bool ch = false;
    for (int n = tid; n < Nn; n += NTHREADS) {
      if (s_status[n] != 0) continue;
      unsigned int m = s_mask[n];
      bool anyKept = false, anyUndec = false;
      while (m) {
        int b = __ffs((int)m) - 1;
        m &= m - 1;
        int dr = b / 5 - 2;
        int dc = b - (b / 5) * 5 - 2;
        unsigned char st = s_status[n + dr * Ww + dc];
        anyKept = anyKept || (st == 1);
        anyUndec = anyUndec || (st == 0);
      }
      if (anyKept)       { s_status[n] = 2; ch = true; }
      else if (!anyUndec){ s_status[n] = 1; ch = true; }
    }
    if (ch) s_changed = 1;   // benign race: all writers store 1
    __syncthreads();
    if (s_changed == 0) break;
  }
  __syncthreads();

  // Epilogue: regressed boxes * keep (matches boxes_c * keep[:,None]).
  for (int n = tid; n < Nn; n += NTHREADS) {
    int r = n / Ww, c = n - r * Ww;
    float x1 = s_lo[c], x2 = s_hi[c], y1 = s_lo[r], y2 = s_hi[r];
    float k = (s_status[n] == 1) ? 1.0f : 0.0f;
    float bbw = x2 - x1 + 1.0f, bbh = y2 - y1 + 1.0f;
    float4 reg = reinterpret_cast<const float4*>(bbox_pred)[n];
    out[n * 5 + 0] = (x1 + reg.x * bbw) * k;
    out[n * 5 + 1] = (y1 + reg.y * bbh) * k;
    out[n * 5 + 2] = (x2 + reg.z * bbw) * k;
    out[n * 5 + 3] = (y2 + reg.w * bbh) * k;
    out[n * 5 + 4] = cls_prob[n] * k;
  }
}

} // namespace

extern "C" void kernel_launch(void* const* d_in, const int* in_sizes, int n_in,
                              void* d_out, int out_size, void* d_ws, size_t ws_size,
                              hipStream_t stream) {
  const float* cls  = (const float*)d_in[0];   // (96,96) float32
  const float* bbox = (const float*)d_in[1];   // (96,96,4) float32
  float* out = (float*)d_out;                  // (9216,5) float32
  hipLaunchKernelGGL(mtcnn_nms_kernel, dim3(1), dim3(NTHREADS), 0, stream,
                     cls, bbox, out);
}

// Round 2
// 95.365 us; speedup vs baseline: 1.6079x; 1.6079x over previous
//
#include <hip/hip_runtime.h>

// MTCNN proposal stage: score threshold + greedy NMS + bbox regression, 96x96 grid.
//
// Exact-equivalence facts (all coords are small integer-valued f32 => exact):
//  - x1(c)=rint(10c/3): deltas 3,4,3 repeating (period 3). Every box 21x21, area 441.
//  - IoU>0.5 <=> inter>294 (inter=294 gives exactly 0.5, excluded).
//  - Suppression pairs exist ONLY at offsets: axial +-1 (always: ow>=17 =>
//    21*17=357>294), axial +-2 (only when 2-step sep==6: 21*15=315>294;
//    sep==7 gives 294, excluded), diagonal +-1,+-1 (unless BOTH seps are 4:
//    17*17=289<294), nothing farther (<=18*15=270<294). Sep pattern depends
//    only on index%3 => pure bit-logic "geometry" mask, zero float IoU math.
//  - Greedy NMS (priority = score desc, index asc; only KEPT boxes suppress)
//    == unique fixpoint of: kept[i] <=> valid[i] && no dominating overlapping
//    neighbor is KEPT && all dominating overlapping neighbors decided.
//    Monotone 3-state relaxation; per-round in-place updates are benign
//    (decisions are final). Progress: the highest-priority UNDEC cell always
//    resolves, so rounds <= N; random input converges in ~depth-of-longest-
//    ascending-chain (~20) rounds.
//
// R2 structure: LDS-staged scores -> bit-logic masks (no global re-reads,
// no IoU floats) -> worklist-compacted relaxation (ping-pong u16 lists
// overlaid on the dead score buffer) with branch-free 12-way status gathers.

namespace {

constexpr int Hh = 96, Ww = 96, Nn = Hh * Ww;
constexpr float THR_SCORE = 0.6f;
constexpr int NT = 512;

__global__ __launch_bounds__(NT) void mtcnn_kernel(
    const float* __restrict__ cls,
    const float* __restrict__ bbox,
    float* __restrict__ out)
{
  __shared__ float s_buf[Nn];             // phase 1-2: scores; rounds: 2x u16 worklists
  __shared__ unsigned short s_mask[Nn];   // 12-bit dominating-overlap mask
  __shared__ unsigned char s_status[Nn];  // 0=UNDEC 1=KEPT 2=SUPP
  __shared__ float s_lo[Ww], s_hi[Ww];
  __shared__ int s_cnt[2];

  unsigned short* const list0 = reinterpret_cast<unsigned short*>(s_buf);
  unsigned short* const list1 = list0 + Nn;

  const int tid = threadIdx.x;

  // Bit b -> flat offset. Negative offsets = earlier flat index = ties dominate (>=).
  const int OFF[12] = {-1, 1, -2, 2, -Ww, Ww, -2*Ww, 2*Ww, -Ww-1, -Ww+1, Ww-1, Ww+1};

  // ---- Phase 1: coordinate tables + stage scores into LDS ----
  if (tid < Ww) {
    float c = (float)tid;
    s_lo[tid] = rintf((2.0f * c) / 0.6f);
    s_hi[tid] = rintf((2.0f * c + 12.0f) / 0.6f);
  }
  for (int q = tid; q < Nn / 4; q += NT)
    reinterpret_cast<float4*>(s_buf)[q] = reinterpret_cast<const float4*>(cls)[q];
  if (tid == 0) s_cnt[0] = 0;
  __syncthreads();

  // ---- Phase 2: per-cell 12-bit suppressor mask + status init ----
  for (int n = tid; n < Nn; n += NT) {
    float si = s_buf[n];
    unsigned int m = 0;
    unsigned char st = 2;
    if (si > THR_SCORE) {
      st = 0;
      int r = n / Ww, c = n - r * Ww;
      int rm = r % 3, cm = c % 3;
      // geometry: which offsets give inter>294 at this (r%3,c%3)
      unsigned int geom = (1u << 0) | (1u << 1) | (1u << 4) | (1u << 5);
      if (cm == 1) geom |= 1u << 2;           // (0,-2): seps 3+3=6
      if (cm == 2) geom |= 1u << 3;           // (0,+2): seps 3+3=6
      if (rm == 1) geom |= 1u << 6;           // (-2,0)
      if (rm == 2) geom |= 1u << 7;           // (+2,0)
      if (!(rm == 2 && cm == 2)) geom |= 1u << 8;   // (-1,-1): not 4&4
      if (!(rm == 2 && cm == 1)) geom |= 1u << 9;   // (-1,+1)
      if (!(rm == 1 && cm == 2)) geom |= 1u << 10;  // (+1,-1)
      if (!(rm == 1 && cm == 1)) geom |= 1u << 11;  // (+1,+1)
      // bounds
      unsigned int inb = 0;
      bool cge1 = c >= 1, cle = c <= Ww - 2, rge1 = r >= 1, rle = r <= Hh - 2;
      if (cge1) inb |= 1u << 0;
      if (cle)  inb |= 1u << 1;
      if (c >= 2)      inb |= 1u << 2;
      if (c <= Ww - 3) inb |= 1u << 3;
      if (rge1) inb |= 1u << 4;
      if (rle)  inb |= 1u << 5;
      if (r >= 2)      inb |= 1u << 6;
      if (r <= Hh - 3) inb |= 1u << 7;
      if (rge1 && cge1) inb |= 1u << 8;
      if (rge1 && cle)  inb |= 1u << 9;
      if (rle && cge1)  inb |= 1u << 10;
      if (rle && cle)   inb |= 1u << 11;
      unsigned int cand = geom & inb;
      #pragma unroll
      for (int b = 0; b < 12; ++b) {
        int j = n + OFF[b];
        j = min(max(j, 0), Nn - 1);          // clamped read; cand gates validity
        float sj = s_buf[j];
        // negative-offset bits (0,2,4,6,8,9): tie -> earlier index dominates
        bool ge = (b == 0) | (b == 2) | (b == 4) | (b == 6) | (b == 8) | (b == 9);
        bool dom = ge ? (sj >= si) : (sj > si);
        if (((cand >> b) & 1u) && (sj > THR_SCORE) && dom) m |= 1u << b;
      }
    }
    s_mask[n] = (unsigned short)m;
    s_status[n] = st;
  }
  __syncthreads();
  // scores in s_buf are dead from here; region reused as worklists.

  // Branch-free resolver: returns 0 resolved / 1 still-undecided.
  auto resolve = [&](int n) -> int {
    unsigned int m = s_mask[n];
    unsigned int km = 0, um = 0;
    #pragma unroll
    for (int b = 0; b < 12; ++b) {
      int j = min(max(n + OFF[b], 0), Nn - 1);
      unsigned char st = s_status[j];
      km |= (unsigned int)(st == 1) << b;
      um |= (unsigned int)(st == 0) << b;
    }
    if (m & km) { s_status[n] = 2; return 0; }
    if (!(m & um)) { s_status[n] = 1; return 0; }
    return 1;
  };

  // ---- Round 0: full pass, build initial worklist ----
  for (int n = tid; n < Nn; n += NT) {
    if (s_status[n] != 0) continue;
    if (resolve(n)) {
      int p = atomicAdd(&s_cnt[0], 1);
      list0[p] = (unsigned short)n;
    }
  }
  __syncthreads();

  // ---- Worklist rounds to fixpoint ----
  int cur = 0;
  while (true) {
    int W = s_cnt[cur];            // uniform: read after closing barrier
    if (W == 0) break;
    if (tid == 0) s_cnt[cur ^ 1] = 0;
    __syncthreads();
    unsigned short* const lc = cur ? list1 : list0;
    unsigned short* const ln = cur ? list0 : list1;
    for (int e = tid; e < W; e += NT) {
      int n = lc[e];
      if (s_status[n] != 0) continue;      // resolved concurrently last round
      if (resolve(n)) {
        int p = atomicAdd(&s_cnt[cur ^ 1], 1);
        ln[p] = (unsigned short)n;
      }
    }
    __syncthreads();
    cur ^= 1;
  }

  // ---- Epilogue: regressed boxes * keep ----
  for (int n = tid; n < Nn; n += NT) {
    int r = n / Ww, c = n - r * Ww;
    float x1 = s_lo[c], x2 = s_hi[c], y1 = s_lo[r], y2 = s_hi[r];
    float k = (s_status[n] == 1) ? 1.0f : 0.0f;
    float bbw = x2 - x1 + 1.0f, bbh = y2 - y1 + 1.0f;
    float4 reg = reinterpret_cast<const float4*>(bbox)[n];
    float sc = cls[n];                     // L1/L2-hot re-read (LDS copy is dead)
    out[n * 5 + 0] = (x1 + reg.x * bbw) * k;
    out[n * 5 + 1] = (y1 + reg.y * bbh) * k;
    out[n * 5 + 2] = (x2 + reg.z * bbw) * k;
    out[n * 5 + 3] = (y2 + reg.w * bbh) * k;
    out[n * 5 + 4] = sc * k;
  }
}

} // namespace

extern "C" void kernel_launch(void* const* d_in, const int* in_sizes, int n_in,
                              void* d_out, int out_size, void* d_ws, size_t ws_size,
                              hipStream_t stream) {
  const float* cls  = (const float*)d_in[0];   // (96,96) f32
  const float* bbox = (const float*)d_in[1];   // (96,96,4) f32
  float* out = (float*)d_out;                  // (9216,5) f32
  hipLaunchKernelGGL(mtcnn_kernel, dim3(1), dim3(NT), 0, stream, cls, bbox, out);
}

// Round 3
// 84.681 us; speedup vs baseline: 1.8107x; 1.1262x over previous
//
#include <hip/hip_runtime.h>

// MTCNN proposal stage: score threshold + greedy NMS + bbox regression, 96x96.
//
// Exact-equivalence facts (validated: R1/R2 passed with absmax 0.0):
//  - Boxes are all 21x21 (area 441), pitch pattern 3/4/3 (period 3).
//  - IoU>0.5 <=> inter>294. Suppression pairs only at 12 offsets:
//    axial +-1 always; axial +-2 iff 2-step separation==6 (index%3 rule);
//    diagonals +-1,+-1 unless both separations are 4; nothing farther.
//    => pure bit-logic geometry mask, zero float IoU math.
//  - Greedy NMS == unique fixpoint of the monotone 3-state relaxation:
//    kept[i] <=> valid[i], no dominating overlapping neighbor KEPT, all
//    dominating overlapping neighbors decided. Priority = (score desc,
//    flat index asc); ties on negative offsets use >=.
//
// R3: BITBOARD relaxation. State (UNDEC, KEPT) and the 12 dominance
// relations are 144-word u64 bitmaps. Flat shifts emulate grid offsets;
// grid-edge wraparound bits are masked by D[b] (which encodes bounds).
// One round = ~100 u64 ops per word, 64 cells at a time, one barrier
// (period-3 change-flag rotation avoids reset/read races). In-place
// monotone updates tolerate stale neighbor reads (decisions are final).

namespace {

constexpr int Hh = 96, Ww = 96, Nn = Hh * Ww;   // 9216
constexpr int NW = Nn / 64;                      // 144 words
constexpr float THR_SCORE = 0.6f;
constexpr int NT = 512;

// Flat offsets per bit b (matches validated R1 enumeration):
// {-1,+1,-2,+2,-96,+96,-192,+192,-97,-95,+95,+97}

__device__ __forceinline__ unsigned long long shift_b(const unsigned long long w[9], int b) {
  // result bit i (of word t) = bitmap bit (64*t + i + OFF[b]); w[j] = W[t-4+j]
  switch (b) {
    case 0:  return (w[4] << 1)  | (w[3] >> 63);   // OFF=-1
    case 1:  return (w[4] >> 1)  | (w[5] << 63);   // +1
    case 2:  return (w[4] << 2)  | (w[3] >> 62);   // -2
    case 3:  return (w[4] >> 2)  | (w[5] << 62);   // +2
    case 4:  return (w[3] << 32) | (w[2] >> 32);   // -96
    case 5:  return (w[5] >> 32) | (w[6] << 32);   // +96
    case 6:  return w[1];                          // -192
    case 7:  return w[7];                          // +192
    case 8:  return (w[3] << 33) | (w[2] >> 31);   // -97
    case 9:  return (w[3] << 31) | (w[2] >> 33);   // -95
    case 10: return (w[5] >> 31) | (w[6] << 33);   // +95
    default: return (w[5] >> 33) | (w[6] << 31);   // +97
  }
}

__global__ __launch_bounds__(NT) void mtcnn_kernel(
    const float* __restrict__ cls,
    const float* __restrict__ bbox,
    float* __restrict__ out)
{
  __shared__ float s_sc[Nn];                       // staged scores (alive whole kernel)
  __shared__ unsigned long long s_D[12][NW];       // dominance bitmaps
  __shared__ unsigned long long s_Up[NW + 8];      // UNDEC bitmap, 4 guard words/side
  __shared__ unsigned long long s_Kp[NW + 8];      // KEPT bitmap
  __shared__ float s_lo[Ww], s_hi[Ww];
  __shared__ int s_ch[3];                          // period-3 change flags

  unsigned long long* const U = s_Up + 4;
  unsigned long long* const K = s_Kp + 4;

  const int tid = threadIdx.x;
  const int lane = tid & 63;
  const int OFF[12] = {-1, 1, -2, 2, -Ww, Ww, -2*Ww, 2*Ww, -Ww-1, -Ww+1, Ww-1, Ww+1};

  // ---- Phase 1: coord tables, stage scores, zero guards/flags ----
  if (tid < Ww) {
    float c = (float)tid;
    s_lo[tid] = rintf((2.0f * c) / 0.6f);
    s_hi[tid] = rintf((2.0f * c + 12.0f) / 0.6f);
  }
  for (int q = tid; q < Nn / 4; q += NT)
    reinterpret_cast<float4*>(s_sc)[q] = reinterpret_cast<const float4*>(cls)[q];
  if (tid < 4) {
    s_Up[tid] = 0ull; s_Kp[tid] = 0ull;
    s_Up[4 + NW + tid] = 0ull; s_Kp[4 + NW + tid] = 0ull;
  }
  if (tid < 3) s_ch[tid] = 0;
  __syncthreads();

  // ---- Phase 2: per-cell dominance mask (validated R1 logic) -> ballots ----
  for (int n = tid; n < Nn; n += NT) {
    float si = s_sc[n];
    unsigned int m = 0;
    bool valid = si > THR_SCORE;
    if (valid) {
      int r = n / Ww, c = n - r * Ww;
      int rm = r % 3, cm = c % 3;
      unsigned int geom = (1u << 0) | (1u << 1) | (1u << 4) | (1u << 5);
      if (cm == 1) geom |= 1u << 2;
      if (cm == 2) geom |= 1u << 3;
      if (rm == 1) geom |= 1u << 6;
      if (rm == 2) geom |= 1u << 7;
      if (!(rm == 2 && cm == 2)) geom |= 1u << 8;
      if (!(rm == 2 && cm == 1)) geom |= 1u << 9;
      if (!(rm == 1 && cm == 2)) geom |= 1u << 10;
      if (!(rm == 1 && cm == 1)) geom |= 1u << 11;
      unsigned int inb = 0;
      bool cge1 = c >= 1, cle = c <= Ww - 2, rge1 = r >= 1, rle = r <= Hh - 2;
      if (cge1) inb |= 1u << 0;
      if (cle)  inb |= 1u << 1;
      if (c >= 2)      inb |= 1u << 2;
      if (c <= Ww - 3) inb |= 1u << 3;
      if (rge1) inb |= 1u << 4;
      if (rle)  inb |= 1u << 5;
      if (r >= 2)      inb |= 1u << 6;
      if (r <= Hh - 3) inb |= 1u << 7;
      if (rge1 && cge1) inb |= 1u << 8;
      if (rge1 && cle)  inb |= 1u << 9;
      if (rle && cge1)  inb |= 1u << 10;
      if (rle && cle)   inb |= 1u << 11;
      unsigned int cand = geom & inb;
      #pragma unroll
      for (int b = 0; b < 12; ++b) {
        int j = n + OFF[b];
        j = min(max(j, 0), Nn - 1);
        float sj = s_sc[j];
        bool ge = (b == 0) | (b == 2) | (b == 4) | (b == 6) | (b == 8) | (b == 9);
        bool dom = ge ? (sj >= si) : (sj > si);
        if (((cand >> b) & 1u) && (sj > THR_SCORE) && dom) m |= 1u << b;
      }
    }
    int w = n >> 6;
    #pragma unroll
    for (int b = 0; b < 12; ++b) {
      unsigned long long bb = __ballot((m >> b) & 1u);
      if (lane == 0) s_D[b][w] = bb;
    }
    unsigned long long vb = __ballot(valid);
    if (lane == 0) { U[w] = vb; K[w] = 0ull; }
  }
  __syncthreads();

  // ---- Relaxation rounds: in-place bitboard Jacobi, 1 barrier/round ----
  // Progress: top-priority undecided cell resolves within 1 barrier of its
  // last dominating neighbor's decision => terminates; no-change round is
  // provably only possible at the full fixpoint.
  for (int it = 0; it < 9999; ++it) {
    const int f = it % 3;
    if (tid == 0) s_ch[(it + 1) % 3] = 0;   // prepare next round's flag
    if (tid < NW) {
      const int t = tid;
      unsigned long long u = U[t];
      if (u) {
        unsigned long long wu[9], wk[9];
        #pragma unroll
        for (int j = 0; j < 9; ++j) { wu[j] = U[t - 4 + j]; wk[j] = K[t - 4 + j]; }
        unsigned long long anyK = 0ull, anyU = 0ull;
        #pragma unroll
        for (int b = 0; b < 12; ++b) {
          unsigned long long d = s_D[b][t];
          anyK |= shift_b(wk, b) & d;
          anyU |= shift_b(wu, b) & d;
        }
        unsigned long long u2 = u & anyU & ~anyK;          // still undecided
        if (u2 != u) {
          K[t] = wk[4] | (u & ~anyU & ~anyK);              // newly kept
          U[t] = u2;
          s_ch[f] = 1;
        }
      }
    }
    __syncthreads();
    if (s_ch[f] == 0) break;   // uniform: read after barrier; flag f not
                               // rewritten until round it+2 (period 3)
  }

  // ---- Epilogue: regressed boxes * keep ----
  for (int n = tid; n < Nn; n += NT) {
    int r = n / Ww, c = n - r * Ww;
    float x1 = s_lo[c], x2 = s_hi[c], y1 = s_lo[r], y2 = s_hi[r];
    float k = (float)((K[n >> 6] >> (n & 63)) & 1ull);
    float bbw = x2 - x1 + 1.0f, bbh = y2 - y1 + 1.0f;
    float4 reg = reinterpret_cast<const float4*>(bbox)[n];
    out[n * 5 + 0] = (x1 + reg.x * bbw) * k;
    out[n * 5 + 1] = (y1 + reg.y * bbh) * k;
    out[n * 5 + 2] = (x2 + reg.z * bbw) * k;
    out[n * 5 + 3] = (y2 + reg.w * bbh) * k;
    out[n * 5 + 4] = s_sc[n] * k;
  }
}

} // namespace

extern "C" void kernel_launch(void* const* d_in, const int* in_sizes, int n_in,
                              void* d_out, int out_size, void* d_ws, size_t ws_size,
                              hipStream_t stream) {
  const float* cls  = (const float*)d_in[0];   // (96,96) f32
  const float* bbox = (const float*)d_in[1];   // (96,96,4) f32
  float* out = (float*)d_out;                  // (9216,5) f32
  hipLaunchKernelGGL(mtcnn_kernel, dim3(1), dim3(NT), 0, stream, cls, bbox, out);
}